// Round 3
// baseline (717.111 us; speedup 1.0000x reference)
//
#include <hip/hip_runtime.h>
#include <hip/hip_bf16.h>

// VGG16 ROI head: roi_pool -> fc6(relu) -> fc7(relu) -> {cls, score}
// Weight-streaming memory-bound (fc6 W = 411 MB fp32). bf16 MFMA 16x16x32.
// R3: 16 k-slabs for fc6/fc7 (grid 1024 = 4 blocks/CU; was 2), wload issued
// AFTER the barrier (in-flight across the MFMA+stage window), odd-step tail
// support. NOTE: dur_us carries ~470us fixed harness restore/poison cost;
// our kernels are the remaining ~230us -> target ~110us.

typedef short short8 __attribute__((ext_vector_type(8)));   // 8 x bf16 bits
typedef float f32x4 __attribute__((ext_vector_type(4)));
typedef int   int4v __attribute__((ext_vector_type(4)));

#define TN 64
#define SK 34      // LDS k-stride in shorts (32 + 2 pad)

static __device__ inline unsigned bfround(float f) {   // fp32 -> bf16 bits (round-half-up)
    return __builtin_bit_cast(unsigned, f) + 0x8000u;
}
static __device__ inline short f2bf(float f) { return (short)(bfround(f) >> 16); }

// ---------------- ROI max-pool: x (1,512,37,50) -> A (128, 25088) bf16 ----------------
__global__ void pool_kernel(const float* __restrict__ x, const float* __restrict__ rois,
                            const int* __restrict__ ridx, short* __restrict__ A) {
    const int r = blockIdx.x;
    const int y1 = (int)floorf(rois[r * 4 + 0] * 0.0625f);
    const int x1 = (int)floorf(rois[r * 4 + 1] * 0.0625f);
    const int y2 = (int)floorf(rois[r * 4 + 2] * 0.0625f);
    const int x2 = (int)floorf(rois[r * 4 + 3] * 0.0625f);
    const int h = y2 - y1 + 1, w = x2 - x1 + 1;
    const float* feat = x + (size_t)ridx[r] * (512 * 37 * 50);
    for (int t = blockIdx.y * 256 + threadIdx.x; t < 25088; t += 2048) {
        const int c = t / 49, b = t % 49, i = b / 7, j = b % 7;
        const int ys = y1 + (i * h) / 7, ye = y1 + ((i + 1) * h + 6) / 7;
        const int xs = x1 + (j * w) / 7, xe = x1 + ((j + 1) * w + 6) / 7;
        const float* f = feat + c * 1850;
        float m = -1e30f;
        for (int yy = ys; yy < ye; yy++)
            for (int xx = xs; xx < xe; xx++)
                m = fmaxf(m, f[yy * 50 + xx]);
        A[(size_t)r * 25088 + t] = f2bf(m);
    }
}

// ---------------- pack w_cls (4096x84) + w_score (4096x21) -> whd (4096x128) ----------------
__global__ void build_whd(const float* __restrict__ wc, const float* __restrict__ wsc,
                          float* __restrict__ whd) {
    const int idx = blockIdx.x * 256 + threadIdx.x;   // < 4096*128
    const int k = idx >> 7, n = idx & 127;
    float v = 0.f;
    if (n < 84) v = wc[k * 84 + n];
    else if (n < 105) v = wsc[k * 21 + (n - 84)];
    whd[idx] = v;
}

// ---------------- M=128 GEMM: part[slab] = A(128xK bf16) @ W(KxN fp32) ----------------
// block: 256 thr (4 waves). Block tile: 128 m x 64 n. K-step = 32. steps >= 2.
// Staging: kp = tid>>4 (k-pair), nb = (tid&15)*4; each thread 2 x float4
// (rows 2kp,2kp+1; cols nb..nb+3) -> cvt bf16, pack k-pairs -> transposed LDS.
// Pipeline: lds[s%2] staged at step s-1 from wset loaded at step s-2.
// wload issued right AFTER the barrier so it rides the MFMA+stage window.
__global__ __launch_bounds__(256, 4)
void gemm128(const short* __restrict__ A, const float* __restrict__ W,
             float* __restrict__ part, int K, int N, int kchunk) {
    __shared__ short lds[2][TN * SK];

    const int tid = threadIdx.x;
    const int lane = tid & 63, wave = tid >> 6;
    const int l15 = lane & 15, quad = lane >> 4;
    const int n_base = blockIdx.x * TN;
    const int kb = blockIdx.y * kchunk;
    const int m0 = wave * 32;
    const int steps = kchunk >> 5;

    const int kp = tid >> 4;          // 0..15
    const int nb = (tid & 15) * 4;    // 0,4,...,60
    const float* gW = W + (size_t)(kb + 2 * kp) * N + n_base + nb;
    const short* gA = A + (size_t)(m0 + l15) * K + kb + quad * 8;

    f32x4 acc[2][4] = {};
    f32x4 wset[2][2];    // [parity][k-row of pair]
    short8 aset[2][2];   // [parity][m-tile]

    auto wload = [&](int s, int c) {
        const float* p = gW + (size_t)s * 32 * N;
        wset[c][0] = *(const f32x4*)p;
        wset[c][1] = *(const f32x4*)(p + N);
    };
    auto aload = [&](int s, int c) {
        const short* p = gA + (size_t)s * 32;
        aset[c][0] = *(const short8*)p;
        aset[c][1] = *(const short8*)(p + (size_t)16 * K);
    };
    auto stage = [&](int c, int buf) {   // convert wset[c] -> lds[buf]
        unsigned* dst = (unsigned*)&lds[buf][0];
#pragma unroll
        for (int i = 0; i < 4; i++) {
            unsigned lo = bfround(wset[c][0][i]) >> 16;
            unsigned hi = bfround(wset[c][1][i]) & 0xffff0000u;
            dst[((nb + i) * SK + 2 * kp) >> 1] = lo | hi;
        }
    };
    auto mfma_step = [&](int C) {
        const short* buf = &lds[C][0];
#pragma unroll
        for (int fn = 0; fn < 4; fn++) {
            const int* src = (const int*)(buf + (fn * 16 + l15) * SK + quad * 8);
            int4v t;
            t[0] = src[0]; t[1] = src[1]; t[2] = src[2]; t[3] = src[3];
            short8 bfr = __builtin_bit_cast(short8, t);
            acc[0][fn] = __builtin_amdgcn_mfma_f32_16x16x32_bf16(aset[C][0], bfr, acc[0][fn], 0, 0, 0);
            acc[1][fn] = __builtin_amdgcn_mfma_f32_16x16x32_bf16(aset[C][1], bfr, acc[1][fn], 0, 0, 0);
        }
    };

    // prologue: stage step 0 into lds[0]; step 1's wload in flight
    wload(0, 0); aload(0, 0);
    stage(0, 0);
    wload(1, 1); aload(1, 1);

    int s = 0;
    for (; s + 1 < steps; s += 2) {
#pragma unroll
        for (int half = 0; half < 2; half++) {
            const int ss = s + half;
            const int C = half;                 // == ss % 2, compile-time
            __syncthreads();
            if (ss + 2 < steps) wload(ss + 2, C);
            mfma_step(C);
            if (ss + 2 < steps) aload(ss + 2, C);
            if (ss + 1 < steps) stage(C ^ 1, C ^ 1);
        }
    }
    if (s < steps) {   // odd tail: ss = steps-1 (even), parity 0
        __syncthreads();
        mfma_step(0);
    }

    float* out = part + (size_t)blockIdx.y * 128 * N;
#pragma unroll
    for (int t = 0; t < 2; t++)
#pragma unroll
        for (int fn = 0; fn < 4; fn++)
#pragma unroll
            for (int r = 0; r < 4; r++) {
                const int row = m0 + 16 * t + quad * 4 + r;
                const int col = n_base + fn * 16 + l15;
                out[(size_t)row * N + col] = acc[t][fn][r];
            }
}

// ---------------- slab-reduce + bias + relu -> bf16 activations ----------------
__global__ void reduce_fc(const float* __restrict__ part, const float* __restrict__ bias,
                          short* __restrict__ out, int N, int nslabs) {
    const int idx = blockIdx.x * 256 + threadIdx.x;   // < 128*N
    const int n = idx % N;
    float s = bias[n];
    for (int sl = 0; sl < nslabs; sl++) s += part[(size_t)sl * 128 * N + idx];
    s = fmaxf(s, 0.f);
    out[idx] = f2bf(s);
}

// ---------------- heads slab-reduce + bias -> d_out (cls 128x84 | score 128x21) ----------------
__global__ void reduce_heads(const float* __restrict__ part, const float* __restrict__ bc,
                             const float* __restrict__ bsc, float* __restrict__ out) {
    const int idx = blockIdx.x * 256 + threadIdx.x;
    if (idx >= 128 * 105) return;
    const int m = idx / 105, n = idx % 105;
    float s = 0.f;
    for (int sl = 0; sl < 32; sl++) s += part[sl * (128 * 128) + m * 128 + n];
    if (n < 84) out[m * 84 + n] = s + bc[n];
    else out[128 * 84 + m * 21 + (n - 84)] = s + bsc[n - 84];
}

extern "C" void kernel_launch(void* const* d_in, const int* in_sizes, int n_in,
                              void* d_out, int out_size, void* d_ws, size_t ws_size,
                              hipStream_t stream) {
    const float* x    = (const float*)d_in[0];
    const float* rois = (const float*)d_in[1];
    const int*   ridx = (const int*)d_in[2];
    const float* w6   = (const float*)d_in[3];
    const float* b6   = (const float*)d_in[4];
    const float* w7   = (const float*)d_in[5];
    const float* b7   = (const float*)d_in[6];
    const float* wc   = (const float*)d_in[7];
    const float* bc   = (const float*)d_in[8];
    const float* wsc  = (const float*)d_in[9];
    const float* bsc  = (const float*)d_in[10];
    float* out = (float*)d_out;

    char* base = (char*)d_ws;
    short* Apool = (short*)base;                         // 128*25088*2 = 6,422,528 B
    float* whd   = (float*)(base + 6422528);             // 4096*128*4  = 2,097,152 B
    short* fc6b  = (short*)(base + 8519680);             // 128*4096*2  = 1,048,576 B
    short* fc7b  = (short*)(base + 9568256);             // 128*4096*2  = 1,048,576 B
    float* slabs = (float*)(base + 10616832);            // max 16*128*4096*4 = 32 MB

    pool_kernel<<<dim3(128, 8), 256, 0, stream>>>(x, rois, ridx, Apool);
    build_whd<<<2048, 256, 0, stream>>>(wc, wsc, whd);

    // fc6: K=25088, N=4096, 16 k-slabs (kchunk 1568 -> 49 steps), 1024 blocks
    gemm128<<<dim3(64, 16), 256, 0, stream>>>(Apool, w6, slabs, 25088, 4096, 1568);
    reduce_fc<<<2048, 256, 0, stream>>>(slabs, b6, fc6b, 4096, 16);

    // fc7: K=4096, N=4096, 16 k-slabs (kchunk 256 -> 8 steps), 1024 blocks
    gemm128<<<dim3(64, 16), 256, 0, stream>>>(fc6b, w7, slabs, 4096, 4096, 256);
    reduce_fc<<<2048, 256, 0, stream>>>(slabs, b7, fc7b, 4096, 16);

    // heads: K=4096, N=128 (padded), 32 k-slabs (kchunk 128 -> 4 steps), 64 blocks
    gemm128<<<dim3(2, 32), 256, 0, stream>>>(fc7b, whd, slabs, 4096, 128, 128);
    reduce_heads<<<53, 256, 0, stream>>>(slabs, bc, bsc, out);
}